// Round 7
// baseline (337.144 us; speedup 1.0000x reference)
//
#include <hip/hip_runtime.h>
#include <stdint.h>

typedef unsigned short u16;
typedef unsigned int u32;
typedef __bf16 b16x8 __attribute__((ext_vector_type(8)));
typedef float f32x4 __attribute__((ext_vector_type(4)));

#define B_ 8
#define S_ 1024
#define H_ 16
#define HD_ 64
#define D_ 1024
#define M_ 8192

__device__ __forceinline__ u16 f2bf(float f) {
  u32 u = __float_as_uint(f);
  return (u16)((u + 0x7fffu + ((u >> 16) & 1u)) >> 16);
}

__device__ __forceinline__ f32x4 mfma16(b16x8 a, b16x8 b, f32x4 c) {
  return __builtin_amdgcn_mfma_f32_16x16x32_bf16(a, b, c, 0, 0, 0);
}

// async global->LDS, 16B per lane. LDS dest = wave-uniform base + lane*16.
__device__ __forceinline__ void cp16(const u16* g, u16* l) {
  __builtin_amdgcn_global_load_lds(
      (const __attribute__((address_space(1))) u32*)(g),
      (__attribute__((address_space(3))) u32*)(l), 16, 0, 0);
}

// ---------------------------------------------------------------------------
// Weight convert+transpose: WT[n][k] = bf16(W[k][n]), W f32 1024x1024.
// ---------------------------------------------------------------------------
__global__ __launch_bounds__(1024) void wconv_kernel(
    const float* __restrict__ w0, const float* __restrict__ w1,
    const float* __restrict__ w2, const float* __restrict__ w3,
    u16* __restrict__ t0, u16* __restrict__ t1, u16* __restrict__ t2,
    u16* __restrict__ t3) {
  __shared__ float tile[32][33];
  const int z = blockIdx.z;
  const float* src = (z == 0) ? w0 : (z == 1) ? w1 : (z == 2) ? w2 : w3;
  u16* dst = (z == 0) ? t0 : (z == 1) ? t1 : (z == 2) ? t2 : t3;
  const int tx = threadIdx.x, ty = threadIdx.y;
  const int x0 = blockIdx.x * 32, y0 = blockIdx.y * 32;
  tile[ty][tx] = src[(size_t)(y0 + ty) * D_ + x0 + tx];
  __syncthreads();
  dst[(size_t)(x0 + ty) * D_ + y0 + tx] = f2bf(tile[tx][ty]);
}

// ---------------------------------------------------------------------------
// x convert: f32 -> bf16, 8M elements, 4/thread
// ---------------------------------------------------------------------------
__global__ __launch_bounds__(256) void xconv_kernel(const float* __restrict__ x,
                                                    u16* __restrict__ xb) {
  const size_t i = ((size_t)blockIdx.x * 256 + threadIdx.x) * 4;
  const float4 v = *(const float4*)(x + i);
  u16 o[4] = {f2bf(v.x), f2bf(v.y), f2bf(v.z), f2bf(v.w)};
  uint2 pack;
  pack.x = ((u32)o[1] << 16) | o[0];
  pack.y = ((u32)o[3] << 16) | o[2];
  *(uint2*)(xb + i) = pack;
}

// ---------------------------------------------------------------------------
// 128x128 GEMM mainloop, BK=64, XOR-swizzled LDS (conflict-free b128 reads):
// global chunk c (8 u16) of row r is stored at LDS chunk c^(r&7); the
// permutation is applied on the cp16 *global* source so the LDS write stays
// linear (wave-uniform base + lane*16). C = A[M,K] @ BT[N,K]^T, fp32 acc.
// ---------------------------------------------------------------------------
__device__ __forceinline__ void gemm128_mainloop(
    const u16* __restrict__ A, const u16* __restrict__ BT, int K, int m0,
    int n0, u16* lds, f32x4 (&acc)[4][4]) {
  const int t = threadIdx.x;
  const int lane = t & 63;
  const int w = t >> 6;
  const int l15 = lane & 15;
  const int q4 = lane >> 4;
  const int mwave = (w >> 1) * 64;
  const int nwave = (w & 1) * 64;

  u16* Alds = lds;         // [128][64], swizzled chunks
  u16* Blds = lds + 8192;  // [128][64]

  const f32x4 zero = {0.f, 0.f, 0.f, 0.f};
  for (int mt = 0; mt < 4; ++mt)
    for (int nt = 0; nt < 4; ++nt) acc[mt][nt] = zero;

  // staging: thread t covers rows rbase + 32c (c=0..3), chunk pos p=t&7,
  // which holds global chunk p ^ (rbase&7)  (row&7 == rbase&7 since 8|32)
  const int rbase = t >> 3;                      // 0..31
  const int scol = ((t & 7) ^ (rbase & 7)) * 8;  // swizzled global col
  const u16* Ag = A + (size_t)(m0 + rbase) * K + scol;
  const u16* Bg = BT + (size_t)(n0 + rbase) * K + scol;

  // fragment read: chunk (kk*4+q4) ^ (l15&7)
  const int sx = l15 & 7;
  const int cA0 = ((0 * 4 + q4) ^ sx) * 8;
  const int cA1 = ((1 * 4 + q4) ^ sx) * 8;

  for (int k0 = 0; k0 < K; k0 += 64) {
    __syncthreads();  // prior iteration's LDS reads complete
    for (int c = 0; c < 4; ++c) {
      cp16(Ag + (size_t)(c * 32) * K + k0, Alds + c * 2048 + t * 8);
      cp16(Bg + (size_t)(c * 32) * K + k0, Blds + c * 2048 + t * 8);
    }
    __syncthreads();  // barrier drains vmcnt -> staging visible

    b16x8 af[4][2], bfr[4][2];
    for (int mt = 0; mt < 4; ++mt) {
      const int row = (mwave + mt * 16 + l15) * 64;
      af[mt][0] = *(const b16x8*)(Alds + row + cA0);
      af[mt][1] = *(const b16x8*)(Alds + row + cA1);
    }
    for (int nt = 0; nt < 4; ++nt) {
      const int row = (nwave + nt * 16 + l15) * 64;
      bfr[nt][0] = *(const b16x8*)(Blds + row + cA0);
      bfr[nt][1] = *(const b16x8*)(Blds + row + cA1);
    }
    for (int mt = 0; mt < 4; ++mt)
      for (int nt = 0; nt < 4; ++nt) {
        acc[mt][nt] = mfma16(af[mt][0], bfr[nt][0], acc[mt][nt]);
        acc[mt][nt] = mfma16(af[mt][1], bfr[nt][1], acc[mt][nt]);
      }
  }
}

// ---------------------------------------------------------------------------
// QKV projection: z=0 -> Q [B,H,S,HD], z=1 -> K [B,H,S,HD], z=2 -> V^T [B,H,HD,S]
// ---------------------------------------------------------------------------
__global__ __launch_bounds__(256) void qkv_gemm_kernel(
    const u16* __restrict__ xb, const u16* __restrict__ wtq,
    const u16* __restrict__ wtk, const u16* __restrict__ wtv,
    const float* __restrict__ bq, const float* __restrict__ bk,
    const float* __restrict__ bv, u16* __restrict__ Q, u16* __restrict__ Kb,
    u16* __restrict__ VT) {
  __shared__ __align__(16) u16 lds[16384];
  const int z = blockIdx.z;
  const u16* BTp = (z == 0) ? wtq : (z == 1) ? wtk : wtv;
  const float* bias = (z == 0) ? bq : (z == 1) ? bk : bv;
  u16* out = (z == 0) ? Q : (z == 1) ? Kb : VT;
  const int m0 = blockIdx.y * 128, n0 = blockIdx.x * 128;

  f32x4 acc[4][4];
  gemm128_mainloop(xb, BTp, D_, m0, n0, lds, acc);

  const int lane = threadIdx.x & 63, w = threadIdx.x >> 6;
  const int l15 = lane & 15, q4 = lane >> 4;
  const int mwave = (w >> 1) * 64, nwave = (w & 1) * 64;

  for (int nt = 0; nt < 4; ++nt) {
    const int n = n0 + nwave + nt * 16 + l15;
    const float bias_v = bias[n];
    const int h = n >> 6, hd = n & 63;
    for (int mt = 0; mt < 4; ++mt) {
      for (int r = 0; r < 4; ++r) {
        const int m = m0 + mwave + mt * 16 + q4 * 4 + r;
        const int b = m >> 10, s = m & 1023;
        const float v = acc[mt][nt][r] + bias_v;
        size_t idx;
        if (z < 2)
          idx = (((size_t)(b * H_ + h)) * S_ + s) * HD_ + hd;
        else
          idx = (((size_t)(b * H_ + h)) * HD_ + hd) * S_ + s;
        out[idx] = f2bf(v);
      }
    }
  }
}

// ---------------------------------------------------------------------------
// Flash attention, fixed-max softmax, software-pipelined K/V staging.
// Block = 64 q x (b,h); wave owns 16 q. PAD 68 (measured conflict-free).
// Q's LDS reused as wave-private P buffer (wave w's Q rows are dead after
// the hoisted aq reads; same-wave DS ops are in-order).
// Mask is staged once into LDS as premultiplied f32 (-14427*m).
// Iteration j issues j+1's K/V global loads right after barrier B so they
// overlap the QK/softmax/PV compute of iteration j.
// ---------------------------------------------------------------------------
#define PAD_ 68
__global__ __launch_bounds__(256) void attn_kernel(
    const u16* __restrict__ Q, const u16* __restrict__ Kb,
    const u16* __restrict__ VT, const int* __restrict__ mask,
    u16* __restrict__ ctx) {
  __shared__ __align__(16) u16 QPlds[64 * PAD_];  // Q tile, then P buffer
  __shared__ __align__(16) u16 Klds[64 * PAD_];
  __shared__ __align__(16) u16 Vlds[64 * PAD_];
  __shared__ __align__(16) float Mlds[1024];  // -14427 * mask[key]

  const int t = threadIdx.x;
  const int lane = t & 63, w = t >> 6;
  const int l15 = lane & 15, q4 = lane >> 4;
  const int bh = blockIdx.y;
  const int b = bh >> 4, h = bh & 15;
  const int q0 = blockIdx.x * 64;

  const u16* Qbh = Q + (size_t)bh * S_ * HD_;
  const u16* Kbh = Kb + (size_t)bh * S_ * HD_;
  const u16* Vbh = VT + (size_t)bh * S_ * HD_;  // [HD][S]
  const int* maskb = mask + b * S_;

  const int srow = t >> 3, scol = (t & 7) * 8;
  {  // stage Q tile [64][64] into padded rows + mask into LDS
    b16x8 q0v = *(const b16x8*)(Qbh + (size_t)(q0 + srow) * HD_ + scol);
    b16x8 q1v = *(const b16x8*)(Qbh + (size_t)(q0 + srow + 32) * HD_ + scol);
    const int4 mv = *(const int4*)(maskb + t * 4);
    *(b16x8*)(QPlds + srow * PAD_ + scol) = q0v;
    *(b16x8*)(QPlds + (srow + 32) * PAD_ + scol) = q1v;
    float4 mf;
    mf.x = -14427.0f * (float)mv.x;
    mf.y = -14427.0f * (float)mv.y;
    mf.z = -14427.0f * (float)mv.z;
    mf.w = -14427.0f * (float)mv.w;
    *(float4*)(Mlds + t * 4) = mf;
  }
  __syncthreads();
  b16x8 aq[2];
  aq[0] = *(const b16x8*)(QPlds + (w * 16 + l15) * PAD_ + q4 * 8);
  aq[1] = *(const b16x8*)(QPlds + (w * 16 + l15) * PAD_ + 32 + q4 * 8);

  const f32x4 zero = {0.f, 0.f, 0.f, 0.f};
  f32x4 acc[4];
  for (int nt = 0; nt < 4; ++nt) acc[nt] = zero;
  float lsum[4] = {0.f, 0.f, 0.f, 0.f};
  u16* Pw = QPlds + w * 16 * PAD_;  // wave-private P region
  const float c1 = 0.18033688f;     // 0.125 * log2(e)

  // prologue: K/V registers for j=0
  b16x8 kv0 = *(const b16x8*)(Kbh + (size_t)srow * HD_ + scol);
  b16x8 kv1 = *(const b16x8*)(Kbh + (size_t)(srow + 32) * HD_ + scol);
  b16x8 vv0 = *(const b16x8*)(Vbh + (size_t)srow * S_ + scol);
  b16x8 vv1 = *(const b16x8*)(Vbh + (size_t)(srow + 32) * S_ + scol);

  for (int j = 0; j < 16; ++j) {
    const int key0 = j * 64;
    __syncthreads();  // (A) prior iteration's K/V LDS reads complete
    *(b16x8*)(Klds + srow * PAD_ + scol) = kv0;
    *(b16x8*)(Klds + (srow + 32) * PAD_ + scol) = kv1;
    *(b16x8*)(Vlds + srow * PAD_ + scol) = vv0;
    *(b16x8*)(Vlds + (srow + 32) * PAD_ + scol) = vv1;
    __syncthreads();  // (B) staging visible

    // prefetch next tile's K/V while computing this one
    if (j < 15) {
      const int kn = key0 + 64;
      kv0 = *(const b16x8*)(Kbh + (size_t)(kn + srow) * HD_ + scol);
      kv1 = *(const b16x8*)(Kbh + (size_t)(kn + srow + 32) * HD_ + scol);
      vv0 = *(const b16x8*)(Vbh + (size_t)srow * S_ + kn + scol);
      vv1 = *(const b16x8*)(Vbh + (size_t)(srow + 32) * S_ + kn + scol);
    }

    float madd[4];
    for (int nt = 0; nt < 4; ++nt) madd[nt] = Mlds[key0 + nt * 16 + l15];

    f32x4 sf[4];
    for (int nt = 0; nt < 4; ++nt) sf[nt] = zero;
    for (int kk = 0; kk < 2; ++kk)
      for (int nt = 0; nt < 4; ++nt) {
        b16x8 bk =
            *(const b16x8*)(Klds + (nt * 16 + l15) * PAD_ + kk * 32 + q4 * 8);
        sf[nt] = mfma16(aq[kk], bk, sf[nt]);
      }

    // fixed-max softmax: p = 2^(s*0.125*log2e + mask*(-14427))
    for (int nt = 0; nt < 4; ++nt)
      for (int r = 0; r < 4; ++r) {
        const float p = __builtin_amdgcn_exp2f(sf[nt][r] * c1 + madd[nt]);
        lsum[r] += p;
        // native bf16 convert (gfx950 V_CVT_PK_BF16_F32, RNE)
        *(__bf16*)(Pw + (q4 * 4 + r) * PAD_ + nt * 16 + l15) = (__bf16)p;
      }
    // P is wave-private: order writes->reads with a wait, no block barrier
    asm volatile("s_waitcnt lgkmcnt(0)" ::: "memory");

    for (int kk = 0; kk < 2; ++kk) {
      b16x8 ap = *(const b16x8*)(Pw + l15 * PAD_ + kk * 32 + q4 * 8);
      for (int nt = 0; nt < 4; ++nt) {
        b16x8 vb =
            *(const b16x8*)(Vlds + (nt * 16 + l15) * PAD_ + kk * 32 + q4 * 8);
        acc[nt] = mfma16(ap, vb, acc[nt]);
      }
    }
  }

  for (int r = 0; r < 4; ++r) {
    for (int off = 1; off < 16; off <<= 1) lsum[r] += __shfl_xor(lsum[r], off);
    lsum[r] = 1.0f / lsum[r];
  }

  for (int nt = 0; nt < 4; ++nt) {
    const int dcol = h * 64 + nt * 16 + l15;
    for (int r = 0; r < 4; ++r) {
      const int srw = q0 + w * 16 + q4 * 4 + r;
      const float o = acc[nt][r] * lsum[r];
      ctx[((size_t)(b * S_ + srw)) * D_ + dcol] = f2bf(o);
    }
  }
}

// ---------------------------------------------------------------------------
// Output projection + bias + residual(x f32) -> y (fp32)
// ---------------------------------------------------------------------------
__global__ __launch_bounds__(256) void out_gemm_kernel(
    const u16* __restrict__ ctx, const u16* __restrict__ wto,
    const float* __restrict__ bo, const float* __restrict__ x,
    float* __restrict__ y) {
  __shared__ __align__(16) u16 lds[16384];
  const int m0 = blockIdx.y * 128, n0 = blockIdx.x * 128;
  f32x4 acc[4][4];
  gemm128_mainloop(ctx, wto, D_, m0, n0, lds, acc);

  const int lane = threadIdx.x & 63, w = threadIdx.x >> 6;
  const int l15 = lane & 15, q4 = lane >> 4;
  const int mwave = (w >> 1) * 64, nwave = (w & 1) * 64;

  for (int nt = 0; nt < 4; ++nt) {
    const int n = n0 + nwave + nt * 16 + l15;
    const float bias = bo[n];
    for (int mt = 0; mt < 4; ++mt) {
      for (int r = 0; r < 4; ++r) {
        const int m = m0 + mwave + mt * 16 + q4 * 4 + r;
        y[(size_t)m * D_ + n] = acc[mt][nt][r] + bias + x[(size_t)m * D_ + n];
      }
    }
  }
}

// ---------------------------------------------------------------------------
// Row LayerNorm: one block per row of 1024, f32 in, f32 out
// ---------------------------------------------------------------------------
__global__ __launch_bounds__(256) void ln_kernel(const float* __restrict__ y,
                                                 const float* __restrict__ g,
                                                 const float* __restrict__ be,
                                                 float* __restrict__ out) {
  const int row = blockIdx.x, t = threadIdx.x;
  const float* yr = y + (size_t)row * D_;
  const float4 v = *(const float4*)(yr + t * 4);
  float s = v.x + v.y + v.z + v.w;
  float ss = v.x * v.x + v.y * v.y + v.z * v.z + v.w * v.w;
  for (int off = 1; off < 64; off <<= 1) {
    s += __shfl_xor(s, off);
    ss += __shfl_xor(ss, off);
  }
  __shared__ float red[8];
  const int w = t >> 6, lane = t & 63;
  if (lane == 0) {
    red[w] = s;
    red[4 + w] = ss;
  }
  __syncthreads();
  s = red[0] + red[1] + red[2] + red[3];
  ss = red[4] + red[5] + red[6] + red[7];
  const float mu = s * (1.f / 1024.f);
  const float var = ss * (1.f / 1024.f) - mu * mu;
  const float rs = rsqrtf(var + 1e-6f);
  const int c = t * 4;
  const float4 gv = *(const float4*)(g + c);
  const float4 bv = *(const float4*)(be + c);
  float4 o;
  o.x = (v.x - mu) * rs * gv.x + bv.x;
  o.y = (v.y - mu) * rs * gv.y + bv.y;
  o.z = (v.z - mu) * rs * gv.z + bv.z;
  o.w = (v.w - mu) * rs * gv.w + bv.w;
  *(float4*)(out + (size_t)row * D_ + c) = o;
}

// ---------------------------------------------------------------------------
extern "C" void kernel_launch(void* const* d_in, const int* in_sizes, int n_in,
                              void* d_out, int out_size, void* d_ws,
                              size_t ws_size, hipStream_t stream) {
  const float* x = (const float*)d_in[0];
  const int* mask = (const int*)d_in[1];
  const float* wq = (const float*)d_in[2];
  const float* bq = (const float*)d_in[3];
  const float* wk = (const float*)d_in[4];
  const float* bk = (const float*)d_in[5];
  const float* wv = (const float*)d_in[6];
  const float* bv = (const float*)d_in[7];
  const float* wo = (const float*)d_in[8];
  const float* bo = (const float*)d_in[9];
  const float* gamma = (const float*)d_in[10];
  const float* beta = (const float*)d_in[11];
  float* out = (float*)d_out;

  char* ws = (char*)d_ws;
  const size_t MB = 1024ull * 1024ull;
  u16* wtq = (u16*)(ws + 0 * MB);
  u16* wtk = (u16*)(ws + 2 * MB);
  u16* wtv = (u16*)(ws + 4 * MB);
  u16* wto = (u16*)(ws + 6 * MB);
  u16* xb = (u16*)(ws + 8 * MB);    // 16MB bf16 x; dead after qkv_gemm
  u16* ctx = (u16*)(ws + 8 * MB);   // aliases xb (written by attn)
  u16* Qb = (u16*)(ws + 24 * MB);   // 16MB; dead after attn
  u16* Kb = (u16*)(ws + 40 * MB);   // 16MB; dead after attn
  u16* VTb = (u16*)(ws + 56 * MB);  // 16MB
  float* y = (float*)(ws + 24 * MB);  // 32MB fp32, aliases Qb+Kb
  // total: 72MB

  wconv_kernel<<<dim3(32, 32, 4), dim3(32, 32), 0, stream>>>(
      wq, wk, wv, wo, wtq, wtk, wtv, wto);
  xconv_kernel<<<8192, 256, 0, stream>>>(x, xb);
  qkv_gemm_kernel<<<dim3(8, 64, 3), 256, 0, stream>>>(
      xb, wtq, wtk, wtv, bq, bk, bv, Qb, Kb, VTb);
  attn_kernel<<<dim3(16, 128), 256, 0, stream>>>(Qb, Kb, VTb, mask, ctx);
  out_gemm_kernel<<<dim3(8, 64), 256, 0, stream>>>(ctx, wto, bo, x, y);
  ln_kernel<<<8192, 256, 0, stream>>>(y, gamma, beta, out);
}

// Round 8
// 312.091 us; speedup vs baseline: 1.0803x; 1.0803x over previous
//
#include <hip/hip_runtime.h>
#include <stdint.h>

typedef unsigned short u16;
typedef unsigned int u32;
typedef __bf16 b16x8 __attribute__((ext_vector_type(8)));
typedef float f32x4 __attribute__((ext_vector_type(4)));

#define B_ 8
#define S_ 1024
#define H_ 16
#define HD_ 64
#define D_ 1024
#define M_ 8192

__device__ __forceinline__ u16 f2bf(float f) {
  u32 u = __float_as_uint(f);
  return (u16)((u + 0x7fffu + ((u >> 16) & 1u)) >> 16);
}
__device__ __forceinline__ u16 bfbits(float f) {
  union {
    __bf16 b;
    u16 u;
  } c;
  c.b = (__bf16)f;  // native V_CVT (RNE)
  return c.u;
}

__device__ __forceinline__ f32x4 mfma16(b16x8 a, b16x8 b, f32x4 c) {
  return __builtin_amdgcn_mfma_f32_16x16x32_bf16(a, b, c, 0, 0, 0);
}

// async global->LDS, 16B per lane. LDS dest = wave-uniform base + lane*16.
__device__ __forceinline__ void cp16(const u16* g, u16* l) {
  __builtin_amdgcn_global_load_lds(
      (const __attribute__((address_space(1))) u32*)(g),
      (__attribute__((address_space(3))) u32*)(l), 16, 0, 0);
}

// ---------------------------------------------------------------------------
// Weight convert+transpose: WT[n][k] = bf16(W[k][n]), W f32 1024x1024.
// ---------------------------------------------------------------------------
__global__ __launch_bounds__(1024) void wconv_kernel(
    const float* __restrict__ w0, const float* __restrict__ w1,
    const float* __restrict__ w2, const float* __restrict__ w3,
    u16* __restrict__ t0, u16* __restrict__ t1, u16* __restrict__ t2,
    u16* __restrict__ t3) {
  __shared__ float tile[32][33];
  const int z = blockIdx.z;
  const float* src = (z == 0) ? w0 : (z == 1) ? w1 : (z == 2) ? w2 : w3;
  u16* dst = (z == 0) ? t0 : (z == 1) ? t1 : (z == 2) ? t2 : t3;
  const int tx = threadIdx.x, ty = threadIdx.y;
  const int x0 = blockIdx.x * 32, y0 = blockIdx.y * 32;
  tile[ty][tx] = src[(size_t)(y0 + ty) * D_ + x0 + tx];
  __syncthreads();
  dst[(size_t)(x0 + ty) * D_ + y0 + tx] = f2bf(tile[tx][ty]);
}

// ---------------------------------------------------------------------------
// x convert: f32 -> bf16, 8M elements, 4/thread
// ---------------------------------------------------------------------------
__global__ __launch_bounds__(256) void xconv_kernel(const float* __restrict__ x,
                                                    u16* __restrict__ xb) {
  const size_t i = ((size_t)blockIdx.x * 256 + threadIdx.x) * 4;
  const float4 v = *(const float4*)(x + i);
  u16 o[4] = {f2bf(v.x), f2bf(v.y), f2bf(v.z), f2bf(v.w)};
  uint2 pack;
  pack.x = ((u32)o[1] << 16) | o[0];
  pack.y = ((u32)o[3] << 16) | o[2];
  *(uint2*)(xb + i) = pack;
}

// ---------------------------------------------------------------------------
// 128x128 GEMM mainloop, BK=64, XOR-swizzled LDS (conflict-free b128 reads).
// ---------------------------------------------------------------------------
__device__ __forceinline__ void gemm128_mainloop(
    const u16* __restrict__ A, const u16* __restrict__ BT, int K, int m0,
    int n0, u16* lds, f32x4 (&acc)[4][4]) {
  const int t = threadIdx.x;
  const int lane = t & 63;
  const int w = t >> 6;
  const int l15 = lane & 15;
  const int q4 = lane >> 4;
  const int mwave = (w >> 1) * 64;
  const int nwave = (w & 1) * 64;

  u16* Alds = lds;         // [128][64], swizzled chunks
  u16* Blds = lds + 8192;  // [128][64]

  const f32x4 zero = {0.f, 0.f, 0.f, 0.f};
  for (int mt = 0; mt < 4; ++mt)
    for (int nt = 0; nt < 4; ++nt) acc[mt][nt] = zero;

  const int rbase = t >> 3;                      // 0..31
  const int scol = ((t & 7) ^ (rbase & 7)) * 8;  // swizzled global col
  const u16* Ag = A + (size_t)(m0 + rbase) * K + scol;
  const u16* Bg = BT + (size_t)(n0 + rbase) * K + scol;

  const int sx = l15 & 7;
  const int cA0 = ((0 * 4 + q4) ^ sx) * 8;
  const int cA1 = ((1 * 4 + q4) ^ sx) * 8;

  for (int k0 = 0; k0 < K; k0 += 64) {
    __syncthreads();
    for (int c = 0; c < 4; ++c) {
      cp16(Ag + (size_t)(c * 32) * K + k0, Alds + c * 2048 + t * 8);
      cp16(Bg + (size_t)(c * 32) * K + k0, Blds + c * 2048 + t * 8);
    }
    __syncthreads();

    b16x8 af[4][2], bfr[4][2];
    for (int mt = 0; mt < 4; ++mt) {
      const int row = (mwave + mt * 16 + l15) * 64;
      af[mt][0] = *(const b16x8*)(Alds + row + cA0);
      af[mt][1] = *(const b16x8*)(Alds + row + cA1);
    }
    for (int nt = 0; nt < 4; ++nt) {
      const int row = (nwave + nt * 16 + l15) * 64;
      bfr[nt][0] = *(const b16x8*)(Blds + row + cA0);
      bfr[nt][1] = *(const b16x8*)(Blds + row + cA1);
    }
    for (int mt = 0; mt < 4; ++mt)
      for (int nt = 0; nt < 4; ++nt) {
        acc[mt][nt] = mfma16(af[mt][0], bfr[nt][0], acc[mt][nt]);
        acc[mt][nt] = mfma16(af[mt][1], bfr[nt][1], acc[mt][nt]);
      }
  }
}

// ---------------------------------------------------------------------------
// QKV projection: z=0 -> Q [B,H,S,HD], z=1 -> K [B,H,S,HD], z=2 -> V^T [B,H,HD,S]
// ---------------------------------------------------------------------------
__global__ __launch_bounds__(256) void qkv_gemm_kernel(
    const u16* __restrict__ xb, const u16* __restrict__ wtq,
    const u16* __restrict__ wtk, const u16* __restrict__ wtv,
    const float* __restrict__ bq, const float* __restrict__ bk,
    const float* __restrict__ bv, u16* __restrict__ Q, u16* __restrict__ Kb,
    u16* __restrict__ VT) {
  __shared__ __align__(16) u16 lds[16384];
  const int z = blockIdx.z;
  const u16* BTp = (z == 0) ? wtq : (z == 1) ? wtk : wtv;
  const float* bias = (z == 0) ? bq : (z == 1) ? bk : bv;
  u16* out = (z == 0) ? Q : (z == 1) ? Kb : VT;
  const int m0 = blockIdx.y * 128, n0 = blockIdx.x * 128;

  f32x4 acc[4][4];
  gemm128_mainloop(xb, BTp, D_, m0, n0, lds, acc);

  const int lane = threadIdx.x & 63, w = threadIdx.x >> 6;
  const int l15 = lane & 15, q4 = lane >> 4;
  const int mwave = (w >> 1) * 64, nwave = (w & 1) * 64;

  for (int nt = 0; nt < 4; ++nt) {
    const int n = n0 + nwave + nt * 16 + l15;
    const float bias_v = bias[n];
    const int h = n >> 6, hd = n & 63;
    for (int mt = 0; mt < 4; ++mt) {
      for (int r = 0; r < 4; ++r) {
        const int m = m0 + mwave + mt * 16 + q4 * 4 + r;
        const int b = m >> 10, s = m & 1023;
        const float v = acc[mt][nt][r] + bias_v;
        size_t idx;
        if (z < 2)
          idx = (((size_t)(b * H_ + h)) * S_ + s) * HD_ + hd;
        else
          idx = (((size_t)(b * H_ + h)) * HD_ + hd) * S_ + s;
        out[idx] = f2bf(v);
      }
    }
  }
}

// ---------------------------------------------------------------------------
// Flash attention, fixed-max softmax, transposed-score formulation.
// S^T = K·Q^T (A=K-frag, B=Q-frag: same LDS reads as before, swapped args).
// Lane then holds P^T[key=q4*4+r][q=l15]: 4 consecutive keys at fixed q ->
// P stored [q][key] with 4 ds_write_b64; PV computed as O^T = V^T·P
// (A=V-frag, B=P-frag read as ds_read_b128 from row q=l15).
// Grid swizzle: id = qt*128 + bh so all 16 q-tiles of one bh share an XCD
// (id%8 == bh%8) -> K/V re-reads hit that XCD's L2 instead of HBM.
// Q LDS (stride 72, 16B-aligned rows) doubles as the wave-private P buffer.
// ---------------------------------------------------------------------------
#define PAD_ 68   // K/V row stride (measured conflict-free)
#define QPAD_ 72  // Q/P row stride (144B = 16B-aligned for b128)
__global__ __launch_bounds__(256) void attn_kernel(
    const u16* __restrict__ Q, const u16* __restrict__ Kb,
    const u16* __restrict__ VT, const int* __restrict__ mask,
    u16* __restrict__ ctx) {
  __shared__ __align__(16) u16 QPlds[64 * QPAD_];  // Q tile, then P buffer
  __shared__ __align__(16) u16 Klds[64 * PAD_];
  __shared__ __align__(16) u16 Vlds[64 * PAD_];
  __shared__ __align__(16) float Mlds[1024];  // -14427 * mask[key]

  const int t = threadIdx.x;
  const int lane = t & 63, w = t >> 6;
  const int l15 = lane & 15, q4 = lane >> 4;
  const int id = blockIdx.x;
  const int bh = id & 127;  // XCD = id%8 = bh%8 -> q-tiles of a bh co-locate
  const int b = bh >> 4, h = bh & 15;
  const int q0 = (id >> 7) * 64;

  const u16* Qbh = Q + (size_t)bh * S_ * HD_;
  const u16* Kbh = Kb + (size_t)bh * S_ * HD_;
  const u16* Vbh = VT + (size_t)bh * S_ * HD_;  // [HD][S]
  const int* maskb = mask + b * S_;

  const int srow = t >> 3, scol = (t & 7) * 8;
  {  // stage Q tile [64][64] + mask into LDS
    b16x8 q0v = *(const b16x8*)(Qbh + (size_t)(q0 + srow) * HD_ + scol);
    b16x8 q1v = *(const b16x8*)(Qbh + (size_t)(q0 + srow + 32) * HD_ + scol);
    const int4 mv = *(const int4*)(maskb + t * 4);
    *(b16x8*)(QPlds + srow * QPAD_ + scol) = q0v;
    *(b16x8*)(QPlds + (srow + 32) * QPAD_ + scol) = q1v;
    float4 mf;
    mf.x = -14427.0f * (float)mv.x;
    mf.y = -14427.0f * (float)mv.y;
    mf.z = -14427.0f * (float)mv.z;
    mf.w = -14427.0f * (float)mv.w;
    *(float4*)(Mlds + t * 4) = mf;
  }
  __syncthreads();
  // Q B-frags (lane holds Q[q=l15][d=q4*8+j]), wave-private rows
  b16x8 aq[2];
  aq[0] = *(const b16x8*)(QPlds + (w * 16 + l15) * QPAD_ + q4 * 8);
  aq[1] = *(const b16x8*)(QPlds + (w * 16 + l15) * QPAD_ + 32 + q4 * 8);

  const f32x4 zero = {0.f, 0.f, 0.f, 0.f};
  f32x4 acc[4];  // O^T tiles: acc[nt] row d=nt*16+q4*4+r, col q=l15
  for (int nt = 0; nt < 4; ++nt) acc[nt] = zero;
  float lsum = 0.f;                      // partial row-sum for q=l15
  u16* Pw = QPlds + w * 16 * QPAD_;      // wave-private P: [q(16)][key(64)]
  const float c1 = 0.18033688f;          // 0.125 * log2(e)

  // prologue: K/V registers for j=0
  b16x8 kv0 = *(const b16x8*)(Kbh + (size_t)srow * HD_ + scol);
  b16x8 kv1 = *(const b16x8*)(Kbh + (size_t)(srow + 32) * HD_ + scol);
  b16x8 vv0 = *(const b16x8*)(Vbh + (size_t)srow * S_ + scol);
  b16x8 vv1 = *(const b16x8*)(Vbh + (size_t)(srow + 32) * S_ + scol);

  for (int j = 0; j < 16; ++j) {
    const int key0 = j * 64;
    __syncthreads();  // (A) prior iteration's K/V LDS reads complete
    *(b16x8*)(Klds + srow * PAD_ + scol) = kv0;
    *(b16x8*)(Klds + (srow + 32) * PAD_ + scol) = kv1;
    *(b16x8*)(Vlds + srow * PAD_ + scol) = vv0;
    *(b16x8*)(Vlds + (srow + 32) * PAD_ + scol) = vv1;
    __syncthreads();  // (B) staging visible

    if (j < 15) {  // prefetch next tile's K/V during compute
      const int kn = key0 + 64;
      kv0 = *(const b16x8*)(Kbh + (size_t)(kn + srow) * HD_ + scol);
      kv1 = *(const b16x8*)(Kbh + (size_t)(kn + srow + 32) * HD_ + scol);
      vv0 = *(const b16x8*)(Vbh + (size_t)srow * S_ + kn + scol);
      vv1 = *(const b16x8*)(Vbh + (size_t)(srow + 32) * S_ + kn + scol);
    }

    // S^T = K·Q^T: sf[nt] rows key=nt*16+q4*4+r, col q=l15
    f32x4 sf[4];
    for (int nt = 0; nt < 4; ++nt) sf[nt] = zero;
    for (int kk = 0; kk < 2; ++kk)
      for (int nt = 0; nt < 4; ++nt) {
        b16x8 bk =
            *(const b16x8*)(Klds + (nt * 16 + l15) * PAD_ + kk * 32 + q4 * 8);
        sf[nt] = mfma16(bk, aq[kk], sf[nt]);
      }

    // fixed-max softmax; mask indexed by key (row) -> broadcast float4
    for (int nt = 0; nt < 4; ++nt) {
      const float4 mk = *(const float4*)(Mlds + key0 + nt * 16 + q4 * 4);
      float p0 = __builtin_amdgcn_exp2f(sf[nt][0] * c1 + mk.x);
      float p1 = __builtin_amdgcn_exp2f(sf[nt][1] * c1 + mk.y);
      float p2 = __builtin_amdgcn_exp2f(sf[nt][2] * c1 + mk.z);
      float p3 = __builtin_amdgcn_exp2f(sf[nt][3] * c1 + mk.w);
      lsum += (p0 + p1) + (p2 + p3);
      uint2 pk;
      pk.x = ((u32)bfbits(p1) << 16) | bfbits(p0);
      pk.y = ((u32)bfbits(p3) << 16) | bfbits(p2);
      // P[q=l15][key=nt*16+q4*4 .. +3]: 4 consecutive keys, one b64 write
      *(uint2*)(Pw + l15 * QPAD_ + nt * 16 + q4 * 4) = pk;
    }
    // wave-private handoff: drain the 4 P writes only
    asm volatile("s_waitcnt lgkmcnt(0)" ::: "memory");

    // O^T += V^T·P: A=V-frag (same read as before), B=P-frag (b128 row read)
    for (int kk = 0; kk < 2; ++kk) {
      b16x8 bp = *(const b16x8*)(Pw + l15 * QPAD_ + kk * 32 + q4 * 8);
      for (int nt = 0; nt < 4; ++nt) {
        b16x8 vb =
            *(const b16x8*)(Vlds + (nt * 16 + l15) * PAD_ + kk * 32 + q4 * 8);
        acc[nt] = mfma16(vb, bp, acc[nt]);
      }
    }
  }

  // row-sum: quads hold disjoint key quarters -> reduce across quads
  lsum += __shfl_xor(lsum, 16);
  lsum += __shfl_xor(lsum, 32);
  const float inv = 1.0f / lsum;

  // epilogue: lane writes 4 consecutive d at fixed row s -> dwordx2 stores
  const int srw = q0 + w * 16 + l15;
  u16* crow = ctx + ((size_t)(b * S_ + srw)) * D_ + h * 64;
  for (int nt = 0; nt < 4; ++nt) {
    uint2 pk;
    pk.x = ((u32)bfbits(acc[nt][1] * inv) << 16) | bfbits(acc[nt][0] * inv);
    pk.y = ((u32)bfbits(acc[nt][3] * inv) << 16) | bfbits(acc[nt][2] * inv);
    *(uint2*)(crow + nt * 16 + q4 * 4) = pk;
  }
}

// ---------------------------------------------------------------------------
// Output projection + bias + residual(x f32) -> y (fp32)
// ---------------------------------------------------------------------------
__global__ __launch_bounds__(256) void out_gemm_kernel(
    const u16* __restrict__ ctx, const u16* __restrict__ wto,
    const float* __restrict__ bo, const float* __restrict__ x,
    float* __restrict__ y) {
  __shared__ __align__(16) u16 lds[16384];
  const int m0 = blockIdx.y * 128, n0 = blockIdx.x * 128;
  f32x4 acc[4][4];
  gemm128_mainloop(ctx, wto, D_, m0, n0, lds, acc);

  const int lane = threadIdx.x & 63, w = threadIdx.x >> 6;
  const int l15 = lane & 15, q4 = lane >> 4;
  const int mwave = (w >> 1) * 64, nwave = (w & 1) * 64;

  for (int nt = 0; nt < 4; ++nt) {
    const int n = n0 + nwave + nt * 16 + l15;
    const float bias = bo[n];
    for (int mt = 0; mt < 4; ++mt) {
      for (int r = 0; r < 4; ++r) {
        const int m = m0 + mwave + mt * 16 + q4 * 4 + r;
        y[(size_t)m * D_ + n] = acc[mt][nt][r] + bias + x[(size_t)m * D_ + n];
      }
    }
  }
}

// ---------------------------------------------------------------------------
// Row LayerNorm: one block per row of 1024, f32 in, f32 out
// ---------------------------------------------------------------------------
__global__ __launch_bounds__(256) void ln_kernel(const float* __restrict__ y,
                                                 const float* __restrict__ g,
                                                 const float* __restrict__ be,
                                                 float* __restrict__ out) {
  const int row = blockIdx.x, t = threadIdx.x;
  const float* yr = y + (size_t)row * D_;
  const float4 v = *(const float4*)(yr + t * 4);
  float s = v.x + v.y + v.z + v.w;
  float ss = v.x * v.x + v.y * v.y + v.z * v.z + v.w * v.w;
  for (int off = 1; off < 64; off <<= 1) {
    s += __shfl_xor(s, off);
    ss += __shfl_xor(ss, off);
  }
  __shared__ float red[8];
  const int w = t >> 6, lane = t & 63;
  if (lane == 0) {
    red[w] = s;
    red[4 + w] = ss;
  }
  __syncthreads();
  s = red[0] + red[1] + red[2] + red[3];
  ss = red[4] + red[5] + red[6] + red[7];
  const float mu = s * (1.f / 1024.f);
  const float var = ss * (1.f / 1024.f) - mu * mu;
  const float rs = rsqrtf(var + 1e-6f);
  const int c = t * 4;
  const float4 gv = *(const float4*)(g + c);
  const float4 bv = *(const float4*)(be + c);
  float4 o;
  o.x = (v.x - mu) * rs * gv.x + bv.x;
  o.y = (v.y - mu) * rs * gv.y + bv.y;
  o.z = (v.z - mu) * rs * gv.z + bv.z;
  o.w = (v.w - mu) * rs * gv.w + bv.w;
  *(float4*)(out + (size_t)row * D_ + c) = o;
}

// ---------------------------------------------------------------------------
extern "C" void kernel_launch(void* const* d_in, const int* in_sizes, int n_in,
                              void* d_out, int out_size, void* d_ws,
                              size_t ws_size, hipStream_t stream) {
  const float* x = (const float*)d_in[0];
  const int* mask = (const int*)d_in[1];
  const float* wq = (const float*)d_in[2];
  const float* bq = (const float*)d_in[3];
  const float* wk = (const float*)d_in[4];
  const float* bk = (const float*)d_in[5];
  const float* wv = (const float*)d_in[6];
  const float* bv = (const float*)d_in[7];
  const float* wo = (const float*)d_in[8];
  const float* bo = (const float*)d_in[9];
  const float* gamma = (const float*)d_in[10];
  const float* beta = (const float*)d_in[11];
  float* out = (float*)d_out;

  char* ws = (char*)d_ws;
  const size_t MB = 1024ull * 1024ull;
  u16* wtq = (u16*)(ws + 0 * MB);
  u16* wtk = (u16*)(ws + 2 * MB);
  u16* wtv = (u16*)(ws + 4 * MB);
  u16* wto = (u16*)(ws + 6 * MB);
  u16* xb = (u16*)(ws + 8 * MB);    // 16MB bf16 x; dead after qkv_gemm
  u16* ctx = (u16*)(ws + 8 * MB);   // aliases xb (written by attn)
  u16* Qb = (u16*)(ws + 24 * MB);   // 16MB; dead after attn
  u16* Kb = (u16*)(ws + 40 * MB);   // 16MB; dead after attn
  u16* VTb = (u16*)(ws + 56 * MB);  // 16MB
  float* y = (float*)(ws + 24 * MB);  // 32MB fp32, aliases Qb+Kb
  // total: 72MB

  wconv_kernel<<<dim3(32, 32, 4), dim3(32, 32), 0, stream>>>(
      wq, wk, wv, wo, wtq, wtk, wtv, wto);
  xconv_kernel<<<8192, 256, 0, stream>>>(x, xb);
  qkv_gemm_kernel<<<dim3(8, 64, 3), 256, 0, stream>>>(
      xb, wtq, wtk, wtv, bq, bk, bv, Qb, Kb, VTb);
  attn_kernel<<<2048, 256, 0, stream>>>(Qb, Kb, VTb, mask, ctx);
  out_gemm_kernel<<<dim3(8, 64), 256, 0, stream>>>(ctx, wto, bo, x, y);
  ln_kernel<<<8192, 256, 0, stream>>>(y, gamma, beta, out);
}